// Round 1
// baseline (84.264 us; speedup 1.0000x reference)
//
#include <hip/hip_runtime.h>

#define BB 32
#define SS 2048
#define VV 516
#define NPART 256   // kernel-2 block count = BB * (SS/256)

__device__ inline float waveReduceSum(float v) {
    #pragma unroll
    for (int off = 32; off > 0; off >>= 1) v += __shfl_down(v, off, 64);
    return v;
}

// Pass 1: lseS[b,v] = log(sum_s exp(x[b,v,s])).  One block per (b,v) row.
__global__ __launch_bounds__(256) void hl_lse_s(const float* __restrict__ out,
                                                float* __restrict__ lseS) {
    __shared__ float lds[4];
    const float* row = out + (size_t)blockIdx.x * SS;
    int t = threadIdx.x;
    float4 a = *(const float4*)(row + t * 4);
    float4 b = *(const float4*)(row + 1024 + t * 4);
    float s = __expf(a.x) + __expf(a.y) + __expf(a.z) + __expf(a.w)
            + __expf(b.x) + __expf(b.y) + __expf(b.z) + __expf(b.w);
    s = waveReduceSum(s);
    int lane = t & 63, w = t >> 6;
    if (lane == 0) lds[w] = s;
    __syncthreads();
    if (t == 0) lseS[blockIdx.x] = __logf(lds[0] + lds[1] + lds[2] + lds[3]);
}

// Pass 2: per (b, s-chunk) block; thread owns one s column, loops over v.
// Computes nll (lse over v minus target logit) and penalty-mask value; block
// partial sums -> ws.
__global__ __launch_bounds__(256) void hl_main(const float* __restrict__ out,
                                               const int* __restrict__ target,
                                               const int* __restrict__ ttype,
                                               const float* __restrict__ tval,
                                               const float* __restrict__ coeff,
                                               const float* __restrict__ harm,
                                               const float* __restrict__ lseS,
                                               float* __restrict__ pNll,
                                               float* __restrict__ pMask) {
    __shared__ float lds[4];
    int b = blockIdx.x >> 3;
    int s = ((blockIdx.x & 7) << 8) + threadIdx.x;
    const float* base = out + ((size_t)b * VV) * SS + s;
    const float* lrow = lseS + b * VV;
    int tgt = target[b * SS + s];

    float sum = 0.f, best = -1e30f, xt = 0.f;
    int bestIdx = 0;
    #pragma unroll 4
    for (int v = 0; v < VV; ++v) {
        float x = base[(size_t)v * SS];      // coalesced across threads
        sum += __expf(x);                     // K=0 shift is overflow-safe here
        float sc = x - lrow[v];               // softmax_S-normalized score
        bool better = sc > best;              // strict > keeps first index (np tie-break)
        best = better ? sc : best;
        bestIdx = better ? v : bestIdx;
        if (v == tgt) xt = x;
    }
    float nll = __logf(sum) - xt;

    // penalty mask from tables
    int pt = ttype[bestIdx], tt = ttype[tgt];
    float pv = tval[bestIdx], tv = tval[tgt];
    float d = fabsf(pv - tv);
    float pw = (d == 7.f) ? harm[0] : (d == 5.f) ? harm[1] : (d == 3.f) ? harm[2]
             : (d == 4.f) ? harm[3] : (d == 1.f) ? harm[4] : (d == 2.f) ? harm[5]
             : harm[6];
    float w = (pt == 0) ? pw
            : (pt == 1) ? coeff[1] * d * (1.f / 160.f)
            : (pt == 2) ? coeff[2] * d * (1.f / 100.f)
            :             coeff[3] * d * (1.f / 128.f);
    float mask = (pt != tt) ? coeff[0] : w;

    // block reduce nll then mask
    int lane = threadIdx.x & 63, wv = threadIdx.x >> 6;
    float rn = waveReduceSum(nll);
    if (lane == 0) lds[wv] = rn;
    __syncthreads();
    float totN = 0.f;
    if (threadIdx.x == 0) totN = lds[0] + lds[1] + lds[2] + lds[3];
    __syncthreads();
    float rm = waveReduceSum(mask);
    if (lane == 0) lds[wv] = rm;
    __syncthreads();
    if (threadIdx.x == 0) {
        pNll[blockIdx.x]  = totN;
        pMask[blockIdx.x] = lds[0] + lds[1] + lds[2] + lds[3];
    }
}

// Pass 3: reduce NPART partials, produce scalar loss*(1+mean(mask)).
__global__ __launch_bounds__(256) void hl_final(const float* __restrict__ pNll,
                                                const float* __restrict__ pMask,
                                                float* __restrict__ outv) {
    __shared__ float lds[8];
    int t = threadIdx.x;
    float n = pNll[t];
    float m = pMask[t];
    n = waveReduceSum(n);
    m = waveReduceSum(m);
    int lane = t & 63, w = t >> 6;
    if (lane == 0) { lds[w] = n; lds[4 + w] = m; }
    __syncthreads();
    if (t == 0) {
        float tn = lds[0] + lds[1] + lds[2] + lds[3];
        float tm = lds[4] + lds[5] + lds[6] + lds[7];
        const float inv = 1.f / (float)(BB * SS);
        float loss = tn * inv;
        outv[0] = loss * (1.f + tm * inv);
    }
}

extern "C" void kernel_launch(void* const* d_in, const int* in_sizes, int n_in,
                              void* d_out, int out_size, void* d_ws, size_t ws_size,
                              hipStream_t stream) {
    const float* out    = (const float*)d_in[0];
    const int*   target = (const int*)d_in[1];
    const int*   ttype  = (const int*)d_in[2];
    const float* tval   = (const float*)d_in[3];
    const float* coeff  = (const float*)d_in[4];
    const float* harm   = (const float*)d_in[5];

    float* ws    = (float*)d_ws;
    float* lseS  = ws;                   // BB*VV = 16512 floats
    float* pNll  = ws + BB * VV;         // NPART floats
    float* pMask = ws + BB * VV + NPART; // NPART floats

    hl_lse_s<<<BB * VV, 256, 0, stream>>>(out, lseS);
    hl_main<<<BB * (SS / 256), 256, 0, stream>>>(out, target, ttype, tval, coeff,
                                                 harm, lseS, pNll, pMask);
    hl_final<<<1, 256, 0, stream>>>(pNll, pMask, (float*)d_out);
}

// Round 2
// 63.250 us; speedup vs baseline: 1.3323x; 1.3323x over previous
//
#include <hip/hip_runtime.h>

#define BB 32
#define SS 2048
#define VV 516
#define NPART 256
#define NBS (BB * SS)        // 65536 (b,s) pairs

__device__ inline float waveReduceSum(float v) {
    #pragma unroll
    for (int off = 32; off > 0; off >>= 1) v += __shfl_down(v, off, 64);
    return v;
}

// Pass 1: lseS[b,v] = log(sum_s exp(x[b,v,s])).  One block per (b,v) row.
__global__ __launch_bounds__(256) void hl_lse_s(const float* __restrict__ out,
                                                float* __restrict__ lseS) {
    __shared__ float lds[4];
    const float* row = out + (size_t)blockIdx.x * SS;
    int t = threadIdx.x;
    float4 a = *(const float4*)(row + t * 4);
    float4 b = *(const float4*)(row + 1024 + t * 4);
    float s = __expf(a.x) + __expf(a.y) + __expf(a.z) + __expf(a.w)
            + __expf(b.x) + __expf(b.y) + __expf(b.z) + __expf(b.w);
    s = waveReduceSum(s);
    int lane = t & 63, w = t >> 6;
    if (lane == 0) lds[w] = s;
    __syncthreads();
    if (t == 0) lseS[blockIdx.x] = __logf(lds[0] + lds[1] + lds[2] + lds[3]);
}

// Pass 2a: per (v-chunk, s-chunk, b) block; thread owns 4 s-columns (float4),
// loops over its v-range.  Emits per-chunk partials: sumExp, bestScore, bestIdx.
__global__ __launch_bounds__(256) void hl_part(const float* __restrict__ out,
                                               const float* __restrict__ lseS,
                                               float* __restrict__ pSum,
                                               float* __restrict__ pBest,
                                               int* __restrict__ pIdx,
                                               int chunkSize) {
    __shared__ float sLse[520];
    int b = blockIdx.z;
    int v0 = blockIdx.x * chunkSize;
    int v1 = v0 + chunkSize; if (v1 > VV) v1 = VV;
    int nv = v1 - v0;
    for (int i = threadIdx.x; i < nv; i += 256) sLse[i] = lseS[b * VV + v0 + i];
    __syncthreads();

    int s = (blockIdx.y << 10) + (threadIdx.x << 2);     // 4 s per thread
    const float* base = out + ((size_t)b * VV + v0) * SS + s;

    float sum0 = 0.f, sum1 = 0.f, sum2 = 0.f, sum3 = 0.f;
    float b0 = -1e30f, b1 = -1e30f, b2 = -1e30f, b3 = -1e30f;
    int i0 = 0, i1 = 0, i2 = 0, i3 = 0;
    #pragma unroll 4
    for (int v = 0; v < nv; ++v) {
        float4 x = *(const float4*)(base + (size_t)v * SS);
        float l = sLse[v];
        sum0 += __expf(x.x); sum1 += __expf(x.y);
        sum2 += __expf(x.z); sum3 += __expf(x.w);
        float sc0 = x.x - l, sc1 = x.y - l, sc2 = x.z - l, sc3 = x.w - l;
        if (sc0 > b0) { b0 = sc0; i0 = v0 + v; }
        if (sc1 > b1) { b1 = sc1; i1 = v0 + v; }
        if (sc2 > b2) { b2 = sc2; i2 = v0 + v; }
        if (sc3 > b3) { b3 = sc3; i3 = v0 + v; }
    }
    int idx = blockIdx.x * NBS + b * SS + s;             // [chunk][b*s] layout
    *(float4*)(pSum + idx)  = make_float4(sum0, sum1, sum2, sum3);
    *(float4*)(pBest + idx) = make_float4(b0, b1, b2, b3);
    *(int4*)(pIdx + idx)    = make_int4(i0, i1, i2, i3);
}

// Pass 2b: merge chunk partials per (b,s); gather target logit; nll + mask;
// block partial sums.
__global__ __launch_bounds__(256) void hl_comb(const float* __restrict__ out,
                                               const int* __restrict__ target,
                                               const int* __restrict__ ttype,
                                               const float* __restrict__ tval,
                                               const float* __restrict__ coeff,
                                               const float* __restrict__ harm,
                                               const float* __restrict__ pSum,
                                               const float* __restrict__ pBest,
                                               const int* __restrict__ pIdx,
                                               int nchunk,
                                               float* __restrict__ pNll,
                                               float* __restrict__ pMask) {
    __shared__ float lds[4];
    int idx = blockIdx.x * 256 + threadIdx.x;            // (b,s) flat
    int b = idx >> 11, s = idx & 2047;

    float sum = 0.f, best = -1e30f;
    int bestIdx = 0;
    for (int c = 0; c < nchunk; ++c) {                   // ascending: first-idx ties
        int o = c * NBS + idx;
        sum += pSum[o];
        float sc = pBest[o];
        if (sc > best) { best = sc; bestIdx = pIdx[o]; }
    }
    int tgt = target[idx];
    float xt = out[((size_t)b * VV + tgt) * SS + s];
    float nll = __logf(sum) - xt;

    int pt = ttype[bestIdx], tt = ttype[tgt];
    float pv = tval[bestIdx], tv = tval[tgt];
    float d = fabsf(pv - tv);
    float pw = (d == 7.f) ? harm[0] : (d == 5.f) ? harm[1] : (d == 3.f) ? harm[2]
             : (d == 4.f) ? harm[3] : (d == 1.f) ? harm[4] : (d == 2.f) ? harm[5]
             : harm[6];
    float w = (pt == 0) ? pw
            : (pt == 1) ? coeff[1] * d * (1.f / 160.f)
            : (pt == 2) ? coeff[2] * d * (1.f / 100.f)
            :             coeff[3] * d * (1.f / 128.f);
    float mask = (pt != tt) ? coeff[0] : w;

    int lane = threadIdx.x & 63, wv = threadIdx.x >> 6;
    float rn = waveReduceSum(nll);
    if (lane == 0) lds[wv] = rn;
    __syncthreads();
    float totN = 0.f;
    if (threadIdx.x == 0) totN = lds[0] + lds[1] + lds[2] + lds[3];
    __syncthreads();
    float rm = waveReduceSum(mask);
    if (lane == 0) lds[wv] = rm;
    __syncthreads();
    if (threadIdx.x == 0) {
        pNll[blockIdx.x]  = totN;
        pMask[blockIdx.x] = lds[0] + lds[1] + lds[2] + lds[3];
    }
}

// Pass 3: reduce NPART partials -> scalar loss*(1+mean(mask)).
__global__ __launch_bounds__(256) void hl_final(const float* __restrict__ pNll,
                                                const float* __restrict__ pMask,
                                                float* __restrict__ outv) {
    __shared__ float lds[8];
    int t = threadIdx.x;
    float n = waveReduceSum(pNll[t]);
    float m = waveReduceSum(pMask[t]);
    int lane = t & 63, w = t >> 6;
    if (lane == 0) { lds[w] = n; lds[4 + w] = m; }
    __syncthreads();
    if (t == 0) {
        float tn = lds[0] + lds[1] + lds[2] + lds[3];
        float tm = lds[4] + lds[5] + lds[6] + lds[7];
        const float inv = 1.f / (float)NBS;
        outv[0] = (tn * inv) * (1.f + tm * inv);
    }
}

extern "C" void kernel_launch(void* const* d_in, const int* in_sizes, int n_in,
                              void* d_out, int out_size, void* d_ws, size_t ws_size,
                              hipStream_t stream) {
    const float* out    = (const float*)d_in[0];
    const int*   target = (const int*)d_in[1];
    const int*   ttype  = (const int*)d_in[2];
    const float* tval   = (const float*)d_in[3];
    const float* coeff  = (const float*)d_in[4];
    const float* harm   = (const float*)d_in[5];

    float* ws    = (float*)d_ws;
    float* lseS  = ws;                       // BB*VV = 16512
    float* pNll  = ws + BB * VV;             // 256
    float* pMask = pNll + NPART;             // 256
    float* pSum  = pMask + NPART;            // nchunk*NBS (16B-aligned: 17024*4)

    // pick largest v-chunk count whose partials fit in ws
    size_t base = (size_t)(BB * VV + 2 * NPART) * 4;
    int nchunk = 12;
    while (nchunk > 1 && base + (size_t)nchunk * NBS * 12 > ws_size) nchunk >>= 1;
    int chunkSize = (VV + nchunk - 1) / nchunk;

    float* pBest = pSum + (size_t)nchunk * NBS;
    int*   pIdx  = (int*)(pBest + (size_t)nchunk * NBS);

    hl_lse_s<<<BB * VV, 256, 0, stream>>>(out, lseS);
    hl_part<<<dim3(nchunk, 2, BB), 256, 0, stream>>>(out, lseS, pSum, pBest,
                                                     pIdx, chunkSize);
    hl_comb<<<NBS / 256, 256, 0, stream>>>(out, target, ttype, tval, coeff, harm,
                                           pSum, pBest, pIdx, nchunk, pNll, pMask);
    hl_final<<<1, 256, 0, stream>>>(pNll, pMask, (float*)d_out);
}

// Round 3
// 61.034 us; speedup vs baseline: 1.3806x; 1.0363x over previous
//
#include <hip/hip_runtime.h>

#define BB 32
#define SS 2048
#define VV 516
#define NBS (BB * SS)       // 65536 (b,s) pairs
#define NPART 256           // hl_comb block count
#define NCHUNK 16
#define CHUNK 33            // ceil(516/16)

__device__ inline float waveReduceSum(float v) {
    #pragma unroll
    for (int off = 32; off > 0; off >>= 1) v += __shfl_down(v, off, 64);
    return v;
}

// Pass 1: lseS[b,v] = log(sum_s exp(x[b,v,s])).  One block per (b,v) row.
// Also zeroes the last-block counter used by hl_comb.
__global__ __launch_bounds__(256) void hl_lse_s(const float* __restrict__ out,
                                                float* __restrict__ lseS,
                                                int* __restrict__ counter) {
    if (blockIdx.x == 0 && threadIdx.x == 0) counter[0] = 0;
    __shared__ float lds[4];
    const float* row = out + (size_t)blockIdx.x * SS;
    int t = threadIdx.x;
    float4 a = *(const float4*)(row + t * 4);
    float4 b = *(const float4*)(row + 1024 + t * 4);
    float s = __expf(a.x) + __expf(a.y) + __expf(a.z) + __expf(a.w)
            + __expf(b.x) + __expf(b.y) + __expf(b.z) + __expf(b.w);
    s = waveReduceSum(s);
    int lane = t & 63, w = t >> 6;
    if (lane == 0) lds[w] = s;
    __syncthreads();
    if (t == 0) lseS[blockIdx.x] = __logf(lds[0] + lds[1] + lds[2] + lds[3]);
}

// Pass 2a: per (v-chunk, s-half, b) block; thread owns 4 s-columns (float4),
// loops over its v-range.  Emits per-chunk partials (sumExp, bestScore,
// bestIdx) and, from the owning chunk, the target logit xt[b,s].
__global__ __launch_bounds__(256, 4) void hl_part(const float* __restrict__ out,
                                                  const int* __restrict__ target,
                                                  const float* __restrict__ lseS,
                                                  float* __restrict__ pSum,
                                                  float* __restrict__ pBest,
                                                  int* __restrict__ pIdx,
                                                  float* __restrict__ xtArr) {
    __shared__ float sLse[CHUNK];
    int b = blockIdx.z;
    int v0 = blockIdx.x * CHUNK;
    int v1 = v0 + CHUNK; if (v1 > VV) v1 = VV;
    int nv = v1 - v0;
    if (threadIdx.x < nv) sLse[threadIdx.x] = lseS[b * VV + v0 + threadIdx.x];
    __syncthreads();

    int s = (blockIdx.y << 10) + (threadIdx.x << 2);     // 4 s per thread
    int bs = b * SS + s;
    const float* base = out + ((size_t)b * VV + v0) * SS + s;
    int4 tg = *(const int4*)(target + bs);

    float sum0 = 0.f, sum1 = 0.f, sum2 = 0.f, sum3 = 0.f;
    float b0 = -1e30f, b1 = -1e30f, b2 = -1e30f, b3 = -1e30f;
    float xt0 = 0.f, xt1 = 0.f, xt2 = 0.f, xt3 = 0.f;
    int i0 = v0, i1 = v0, i2 = v0, i3 = v0;
    #pragma unroll 8
    for (int v = 0; v < nv; ++v) {
        float4 x = *(const float4*)(base + (size_t)v * SS);
        float l = sLse[v];
        int vg = v0 + v;
        sum0 += __expf(x.x); sum1 += __expf(x.y);
        sum2 += __expf(x.z); sum3 += __expf(x.w);
        float sc0 = x.x - l, sc1 = x.y - l, sc2 = x.z - l, sc3 = x.w - l;
        if (sc0 > b0) { b0 = sc0; i0 = vg; }
        if (sc1 > b1) { b1 = sc1; i1 = vg; }
        if (sc2 > b2) { b2 = sc2; i2 = vg; }
        if (sc3 > b3) { b3 = sc3; i3 = vg; }
        if (vg == tg.x) xt0 = x.x;
        if (vg == tg.y) xt1 = x.y;
        if (vg == tg.z) xt2 = x.z;
        if (vg == tg.w) xt3 = x.w;
    }
    int o = blockIdx.x * NBS + bs;                       // [chunk][b*s]
    *(float4*)(pSum + o)  = make_float4(sum0, sum1, sum2, sum3);
    *(float4*)(pBest + o) = make_float4(b0, b1, b2, b3);
    *(int4*)(pIdx + o)    = make_int4(i0, i1, i2, i3);
    if (tg.x >= v0 && tg.x < v1) xtArr[bs + 0] = xt0;
    if (tg.y >= v0 && tg.y < v1) xtArr[bs + 1] = xt1;
    if (tg.z >= v0 && tg.z < v1) xtArr[bs + 2] = xt2;
    if (tg.w >= v0 && tg.w < v1) xtArr[bs + 3] = xt3;
}

// Pass 2b: merge chunk partials per (b,s); nll + penalty mask; block partial
// sums; last block folds the 256 partials into the scalar output.
__global__ __launch_bounds__(256) void hl_comb(const int* __restrict__ target,
                                               const int* __restrict__ ttype,
                                               const float* __restrict__ tval,
                                               const float* __restrict__ coeff,
                                               const float* __restrict__ harm,
                                               const float* __restrict__ pSum,
                                               const float* __restrict__ pBest,
                                               const int* __restrict__ pIdx,
                                               const float* __restrict__ xtArr,
                                               float* __restrict__ pNll,
                                               float* __restrict__ pMask,
                                               int* __restrict__ counter,
                                               float* __restrict__ outv) {
    __shared__ float lds[8];
    __shared__ bool isLast;
    int idx = blockIdx.x * 256 + threadIdx.x;            // (b,s) flat

    float sum = 0.f, best = -1e30f;
    int bestIdx = 0;
    #pragma unroll
    for (int c = 0; c < NCHUNK; ++c) {                   // ascending: first-idx ties
        int o = c * NBS + idx;
        sum += pSum[o];
        float sc = pBest[o];
        int ii = pIdx[o];
        if (sc > best) { best = sc; bestIdx = ii; }
    }
    int tgt = target[idx];
    float nll = __logf(sum) - xtArr[idx];

    int pt = ttype[bestIdx], tt = ttype[tgt];
    float pv = tval[bestIdx], tv = tval[tgt];
    float d = fabsf(pv - tv);
    float pw = (d == 7.f) ? harm[0] : (d == 5.f) ? harm[1] : (d == 3.f) ? harm[2]
             : (d == 4.f) ? harm[3] : (d == 1.f) ? harm[4] : (d == 2.f) ? harm[5]
             : harm[6];
    float w = (pt == 0) ? pw
            : (pt == 1) ? coeff[1] * d * (1.f / 160.f)
            : (pt == 2) ? coeff[2] * d * (1.f / 100.f)
            :             coeff[3] * d * (1.f / 128.f);
    float mask = (pt != tt) ? coeff[0] : w;

    int lane = threadIdx.x & 63, wv = threadIdx.x >> 6;
    float rn = waveReduceSum(nll);
    if (lane == 0) lds[wv] = rn;
    __syncthreads();
    float totN = (threadIdx.x == 0) ? lds[0] + lds[1] + lds[2] + lds[3] : 0.f;
    __syncthreads();
    float rm = waveReduceSum(mask);
    if (lane == 0) lds[wv] = rm;
    __syncthreads();
    if (threadIdx.x == 0) {
        pNll[blockIdx.x]  = totN;
        pMask[blockIdx.x] = lds[0] + lds[1] + lds[2] + lds[3];
        __threadfence();
        unsigned old = atomicAdd((unsigned*)counter, 1u);
        isLast = (old == NPART - 1);
    }
    __syncthreads();
    if (isLast) {
        __threadfence();                                 // invalidate L1 for partial reads
        int t = threadIdx.x;
        float n = waveReduceSum(pNll[t]);
        float m = waveReduceSum(pMask[t]);
        if (lane == 0) { lds[wv] = n; lds[4 + wv] = m; }
        __syncthreads();
        if (t == 0) {
            float tn = lds[0] + lds[1] + lds[2] + lds[3];
            float tm = lds[4] + lds[5] + lds[6] + lds[7];
            const float inv = 1.f / (float)NBS;
            outv[0] = (tn * inv) * (1.f + tm * inv);
        }
    }
}

extern "C" void kernel_launch(void* const* d_in, const int* in_sizes, int n_in,
                              void* d_out, int out_size, void* d_ws, size_t ws_size,
                              hipStream_t stream) {
    const float* out    = (const float*)d_in[0];
    const int*   target = (const int*)d_in[1];
    const int*   ttype  = (const int*)d_in[2];
    const float* tval   = (const float*)d_in[3];
    const float* coeff  = (const float*)d_in[4];
    const float* harm   = (const float*)d_in[5];

    float* ws      = (float*)d_ws;
    float* lseS    = ws;                         // 16512
    float* pNll    = lseS + BB * VV;             // 256
    float* pMask   = pNll + NPART;               // 256
    int*   counter = (int*)(pMask + NPART);      // 1 (+3 pad)
    float* xtArr   = pMask + NPART + 4;          // 65536  (offset 17028, 16B-aligned)
    float* pSum    = xtArr + NBS;                // NCHUNK*NBS
    float* pBest   = pSum + (size_t)NCHUNK * NBS;
    int*   pIdx    = (int*)(pBest + (size_t)NCHUNK * NBS);

    hl_lse_s<<<BB * VV, 256, 0, stream>>>(out, lseS, counter);
    hl_part<<<dim3(NCHUNK, 2, BB), 256, 0, stream>>>(out, target, lseS, pSum,
                                                     pBest, pIdx, xtArr);
    hl_comb<<<NBS / 256, 256, 0, stream>>>(target, ttype, tval, coeff, harm,
                                           pSum, pBest, pIdx, xtArr,
                                           pNll, pMask, counter, (float*)d_out);
}

// Round 5
// 48.850 us; speedup vs baseline: 1.7250x; 1.2494x over previous
//
#include <hip/hip_runtime.h>

#define BB 32
#define SS 2048
#define VV 516
#define NBS (BB * SS)      // 65536
#define NCHUNK 16
#define NPART 256          // comb block count

__device__ inline float waveReduceSum(float v) {
    #pragma unroll
    for (int o = 32; o > 0; o >>= 1) v += __shfl_down(v, o, 64);
    return v;
}

// One block per (b, v-chunk).  Streams its 32/33 rows from HBM exactly once:
// sub-chunks of 8 rows are staged in LDS; phase 1 computes per-row lse over S
// (wave-reduce), phase 2 scores the rows from LDS along V.
__global__ __launch_bounds__(256) void hl_tile(const float* __restrict__ x,
                                               const int* __restrict__ target,
                                               int* __restrict__ ctr,
                                               float* __restrict__ pSum,
                                               float* __restrict__ pBest,
                                               int* __restrict__ pIdx,
                                               float* __restrict__ xtArr) {
    __shared__ float ldsX[8 * 2048];   // 64 KB: 8 staged rows
    __shared__ float sLse[8];

    if (blockIdx.x == 0 && threadIdx.x == 0) ctr[0] = 0;   // for comb finalize

    const int c = blockIdx.x & 15, b = blockIdx.x >> 4;
    const int v0 = 32 * c + (c > 12 ? c - 12 : 0);         // 12 chunks of 32, 4 of 33
    const int nv = (c >= 12) ? 33 : 32;
    const int tid = threadIdx.x, lane = tid & 63, wv = tid >> 6;

    const int s0 = tid << 2;
    const int bs = b * SS + s0;
    int4 tgA = *(const int4*)(target + bs);
    int4 tgB = *(const int4*)(target + bs + 1024);
    int tg[8] = {tgA.x, tgA.y, tgA.z, tgA.w, tgB.x, tgB.y, tgB.z, tgB.w};

    float sum[8], best[8], xt[8];
    int bi[8];
    #pragma unroll
    for (int i = 0; i < 8; ++i) { sum[i] = 0.f; best[i] = -1e30f; bi[i] = v0; xt[i] = 0.f; }

    const float* xb = x + (size_t)(b * VV + v0) * SS;

    for (int vs = 0; vs < nv; vs += 8) {
        int m = nv - vs; if (m > 8) m = 8;
        // ---- phase 1: wave wv loads rows wv*2, wv*2+1 of this sub-chunk ----
        #pragma unroll
        for (int k = 0; k < 2; ++k) {
            int lr = wv * 2 + k;                       // local row
            if (lr < m) {                              // wave-uniform branch
                const float* row = xb + (size_t)(vs + lr) * SS;
                float4 v[8];
                #pragma unroll
                for (int j = 0; j < 8; ++j)
                    v[j] = *(const float4*)(row + j * 256 + lane * 4);
                float a0 = 0.f, a1 = 0.f, a2 = 0.f, a3 = 0.f;
                #pragma unroll
                for (int j = 0; j < 8; ++j) {
                    *(float4*)(ldsX + lr * 2048 + j * 256 + lane * 4) = v[j];
                    a0 += __expf(v[j].x); a1 += __expf(v[j].y);
                    a2 += __expf(v[j].z); a3 += __expf(v[j].w);
                }
                float ssum = waveReduceSum((a0 + a1) + (a2 + a3));
                if (lane == 0) sLse[lr] = __logf(ssum);
            }
        }
        __syncthreads();
        // ---- phase 2: score m rows from LDS; thread owns 8 s-columns ----
        for (int v = 0; v < m; ++v) {
            float l = sLse[v];
            int vg = v0 + vs + v;
            float4 xa = *(const float4*)(ldsX + v * 2048 + s0);
            float4 xc = *(const float4*)(ldsX + v * 2048 + 1024 + s0);
            float e[8] = {xa.x, xa.y, xa.z, xa.w, xc.x, xc.y, xc.z, xc.w};
            #pragma unroll
            for (int i = 0; i < 8; ++i) {
                sum[i] += __expf(e[i]);
                float sc = e[i] - l;
                if (sc > best[i]) { best[i] = sc; bi[i] = vg; }
                if (vg == tg[i]) xt[i] = e[i];
            }
        }
        __syncthreads();
    }

    // ---- write per-chunk partials ----
    int o = c * NBS + bs;
    *(float4*)(pSum + o)         = make_float4(sum[0], sum[1], sum[2], sum[3]);
    *(float4*)(pSum + o + 1024)  = make_float4(sum[4], sum[5], sum[6], sum[7]);
    *(float4*)(pBest + o)        = make_float4(best[0], best[1], best[2], best[3]);
    *(float4*)(pBest + o + 1024) = make_float4(best[4], best[5], best[6], best[7]);
    *(int4*)(pIdx + o)           = make_int4(bi[0], bi[1], bi[2], bi[3]);
    *(int4*)(pIdx + o + 1024)    = make_int4(bi[4], bi[5], bi[6], bi[7]);
    int v1 = v0 + nv;
    #pragma unroll
    for (int i = 0; i < 8; ++i) {
        int col = (i < 4) ? (s0 + i) : (1024 + s0 + i - 4);
        if (tg[i] >= v0 && tg[i] < v1) xtArr[b * SS + col] = xt[i];
    }
}

// Merge chunk partials per (b,s); nll + penalty mask; block partial sums;
// last block folds the 256 partials into the scalar output.  (R3-proven.)
__global__ __launch_bounds__(256) void hl_comb(const int* __restrict__ target,
                                               const int* __restrict__ ttype,
                                               const float* __restrict__ tval,
                                               const float* __restrict__ coeff,
                                               const float* __restrict__ harm,
                                               const float* __restrict__ pSum,
                                               const float* __restrict__ pBest,
                                               const int* __restrict__ pIdx,
                                               const float* __restrict__ xtArr,
                                               float* __restrict__ pNll,
                                               float* __restrict__ pMask,
                                               int* __restrict__ counter,
                                               float* __restrict__ outv) {
    __shared__ float lds[8];
    __shared__ bool isLast;
    int idx = blockIdx.x * 256 + threadIdx.x;            // (b,s) flat

    float sum = 0.f, best = -1e30f;
    int bestIdx = 0;
    #pragma unroll
    for (int c = 0; c < NCHUNK; ++c) {                   // ascending: first-idx ties
        int o = c * NBS + idx;
        sum += pSum[o];
        float sc = pBest[o];
        int ii = pIdx[o];
        if (sc > best) { best = sc; bestIdx = ii; }
    }
    int tgt = target[idx];
    float nll = __logf(sum) - xtArr[idx];

    int pt = ttype[bestIdx], tt = ttype[tgt];
    float pv = tval[bestIdx], tv = tval[tgt];
    float d = fabsf(pv - tv);
    float pw = (d == 7.f) ? harm[0] : (d == 5.f) ? harm[1] : (d == 3.f) ? harm[2]
             : (d == 4.f) ? harm[3] : (d == 1.f) ? harm[4] : (d == 2.f) ? harm[5]
             : harm[6];
    float w = (pt == 0) ? pw
            : (pt == 1) ? coeff[1] * d * (1.f / 160.f)
            : (pt == 2) ? coeff[2] * d * (1.f / 100.f)
            :             coeff[3] * d * (1.f / 128.f);
    float mask = (pt != tt) ? coeff[0] : w;

    int lane = threadIdx.x & 63, wvv = threadIdx.x >> 6;
    float rn = waveReduceSum(nll);
    if (lane == 0) lds[wvv] = rn;
    __syncthreads();
    float totN = (threadIdx.x == 0) ? lds[0] + lds[1] + lds[2] + lds[3] : 0.f;
    __syncthreads();
    float rm = waveReduceSum(mask);
    if (lane == 0) lds[wvv] = rm;
    __syncthreads();
    if (threadIdx.x == 0) {
        pNll[blockIdx.x]  = totN;
        pMask[blockIdx.x] = lds[0] + lds[1] + lds[2] + lds[3];
        __threadfence();
        unsigned old = atomicAdd((unsigned*)counter, 1u);
        isLast = (old == NPART - 1);
    }
    __syncthreads();
    if (isLast) {
        __threadfence();
        int t = threadIdx.x;
        float n = waveReduceSum(pNll[t]);
        float m = waveReduceSum(pMask[t]);
        if (lane == 0) { lds[wvv] = n; lds[4 + wvv] = m; }
        __syncthreads();
        if (t == 0) {
            float tn = lds[0] + lds[1] + lds[2] + lds[3];
            float tm = lds[4] + lds[5] + lds[6] + lds[7];
            const float inv = 1.f / (float)NBS;
            outv[0] = (tn * inv) * (1.f + tm * inv);
        }
    }
}

extern "C" void kernel_launch(void* const* d_in, const int* in_sizes, int n_in,
                              void* d_out, int out_size, void* d_ws, size_t ws_size,
                              hipStream_t stream) {
    const float* x      = (const float*)d_in[0];
    const int*   target = (const int*)d_in[1];
    const int*   ttype  = (const int*)d_in[2];
    const float* tval   = (const float*)d_in[3];
    const float* coeff  = (const float*)d_in[4];
    const float* harm   = (const float*)d_in[5];

    float* ws    = (float*)d_ws;
    int*   ctr   = (int*)ws;                     // 4 ints
    float* pNll  = ws + 4;                       // 256
    float* pMask = pNll + NPART;                 // 256
    float* xtArr = pMask + NPART;                // 65536 (offset 516, 16B-aligned)
    float* pSum  = xtArr + NBS;                  // 16*65536
    float* pBest = pSum + (size_t)NCHUNK * NBS;  // 16*65536
    int*   pIdx  = (int*)(pBest + (size_t)NCHUNK * NBS);

    hl_tile<<<BB * NCHUNK, 256, 0, stream>>>(x, target, ctr, pSum, pBest,
                                             pIdx, xtArr);
    hl_comb<<<NBS / 256, 256, 0, stream>>>(target, ttype, tval, coeff, harm,
                                           pSum, pBest, pIdx, xtArr,
                                           pNll, pMask, ctr, (float*)d_out);
}

// Round 6
// 46.975 us; speedup vs baseline: 1.7938x; 1.0399x over previous
//
#include <hip/hip_runtime.h>

#define BB 32
#define SS 2048
#define VV 516
#define NBS (BB * SS)      // 65536
#define NCHUNK 16
#define NPART 256          // comb block count

__device__ inline float waveReduceSum(float v) {
    #pragma unroll
    for (int o = 32; o > 0; o >>= 1) v += __shfl_down(v, o, 64);
    return v;
}

// One block per (b, v-chunk), 512 threads (8 waves).  Streams its 32/33 rows
// from HBM exactly once in 8-row sub-chunks; LDS holds exp(x).  Phase 1: wave
// w loads row w, computes e=exp(x), writes e to LDS, wave-reduces the row sum
// -> reciprocal.  Phase 2: thread owns 4 s-columns; per row accumulates
// sum_v e and argmax of the softmax_S ratio e*rcp (monotone-equivalent to
// x - lseS).  Target logit gathered from LDS once per sub-chunk (xt=log(e)).
__global__ __launch_bounds__(512, 4) void hl_tile(const float* __restrict__ x,
                                                  const int* __restrict__ target,
                                                  int* __restrict__ ctr,
                                                  float* __restrict__ pSum,
                                                  float* __restrict__ pBest,
                                                  int* __restrict__ pIdx,
                                                  float* __restrict__ xtArr) {
    __shared__ float ldsE[8 * 2048];   // 64 KB: 8 staged rows of exp(x)
    __shared__ float sRcp[8];

    if (blockIdx.x == 0 && threadIdx.x == 0) ctr[0] = 0;   // comb finalize ctr

    const int c = blockIdx.x & 15, b = blockIdx.x >> 4;
    const int v0 = 32 * c + (c > 12 ? c - 12 : 0);         // 12x32 + 4x33 = 516
    const int nv = (c >= 12) ? 33 : 32;
    const int tid = threadIdx.x, lane = tid & 63, wv = tid >> 6;

    const int s0 = tid << 2;                               // 4 s-cols per thread
    const int bs = b * SS + s0;
    int4 tg4 = *(const int4*)(target + bs);
    int tg[4] = {tg4.x, tg4.y, tg4.z, tg4.w};

    float sum[4], best[4], xt[4];
    int bi[4];
    #pragma unroll
    for (int i = 0; i < 4; ++i) { sum[i] = 0.f; best[i] = -1.f; bi[i] = v0; xt[i] = 0.f; }

    const float* xb = x + (size_t)(b * VV + v0) * SS;

    for (int vs = 0; vs < nv; vs += 8) {
        int m = nv - vs; if (m > 8) m = 8;
        // ---- phase 1: wave wv owns local row wv ----
        if (wv < m) {                                      // wave-uniform
            const float* row = xb + (size_t)(vs + wv) * SS;
            float4 v[8];
            #pragma unroll
            for (int j = 0; j < 8; ++j)
                v[j] = *(const float4*)(row + j * 256 + lane * 4);
            float a0 = 0.f, a1 = 0.f, a2 = 0.f, a3 = 0.f;
            #pragma unroll
            for (int j = 0; j < 8; ++j) {
                float4 e;
                e.x = __expf(v[j].x); e.y = __expf(v[j].y);
                e.z = __expf(v[j].z); e.w = __expf(v[j].w);
                *(float4*)(ldsE + wv * 2048 + j * 256 + lane * 4) = e;
                a0 += e.x; a1 += e.y; a2 += e.z; a3 += e.w;
            }
            float ssum = waveReduceSum((a0 + a1) + (a2 + a3));
            if (lane == 0) sRcp[wv] = 1.f / ssum;
        }
        __syncthreads();
        // ---- phase 2: score m rows from LDS ----
        for (int v = 0; v < m; ++v) {
            float r = sRcp[v];
            int vg = v0 + vs + v;
            float4 e4 = *(const float4*)(ldsE + v * 2048 + s0);
            float e[4] = {e4.x, e4.y, e4.z, e4.w};
            #pragma unroll
            for (int i = 0; i < 4; ++i) {
                sum[i] += e[i];
                float sc = e[i] * r;                       // softmax_S value
                if (sc > best[i]) { best[i] = sc; bi[i] = vg; }
            }
        }
        // ---- target gather (rare lanes active) ----
        #pragma unroll
        for (int i = 0; i < 4; ++i) {
            int lr = tg[i] - (v0 + vs);
            if (lr >= 0 && lr < m) xt[i] = __logf(ldsE[lr * 2048 + s0 + i]);
        }
        __syncthreads();
    }

    // ---- write per-chunk partials ----
    int o = c * NBS + bs;
    *(float4*)(pSum + o)  = make_float4(sum[0], sum[1], sum[2], sum[3]);
    *(float4*)(pBest + o) = make_float4(best[0], best[1], best[2], best[3]);
    *(int4*)(pIdx + o)    = make_int4(bi[0], bi[1], bi[2], bi[3]);
    int v1 = v0 + nv;
    #pragma unroll
    for (int i = 0; i < 4; ++i)
        if (tg[i] >= v0 && tg[i] < v1) xtArr[bs + i] = xt[i];
}

// Merge chunk partials per (b,s); nll + penalty mask; block partial sums;
// last block folds the 256 partials into the scalar output.
__global__ __launch_bounds__(256) void hl_comb(const int* __restrict__ target,
                                               const int* __restrict__ ttype,
                                               const float* __restrict__ tval,
                                               const float* __restrict__ coeff,
                                               const float* __restrict__ harm,
                                               const float* __restrict__ pSum,
                                               const float* __restrict__ pBest,
                                               const int* __restrict__ pIdx,
                                               const float* __restrict__ xtArr,
                                               float* __restrict__ pNll,
                                               float* __restrict__ pMask,
                                               int* __restrict__ counter,
                                               float* __restrict__ outv) {
    __shared__ float lds[8];
    __shared__ bool isLast;
    int idx = blockIdx.x * 256 + threadIdx.x;            // (b,s) flat

    float sum = 0.f, best = -1e30f;
    int bestIdx = 0;
    #pragma unroll
    for (int c = 0; c < NCHUNK; ++c) {                   // ascending: first-idx ties
        int o = c * NBS + idx;
        sum += pSum[o];
        float sc = pBest[o];
        int ii = pIdx[o];
        if (sc > best) { best = sc; bestIdx = ii; }
    }
    int tgt = target[idx];
    float nll = __logf(sum) - xtArr[idx];

    int pt = ttype[bestIdx], tt = ttype[tgt];
    float pv = tval[bestIdx], tv = tval[tgt];
    float d = fabsf(pv - tv);
    float pw = (d == 7.f) ? harm[0] : (d == 5.f) ? harm[1] : (d == 3.f) ? harm[2]
             : (d == 4.f) ? harm[3] : (d == 1.f) ? harm[4] : (d == 2.f) ? harm[5]
             : harm[6];
    float w = (pt == 0) ? pw
            : (pt == 1) ? coeff[1] * d * (1.f / 160.f)
            : (pt == 2) ? coeff[2] * d * (1.f / 100.f)
            :             coeff[3] * d * (1.f / 128.f);
    float mask = (pt != tt) ? coeff[0] : w;

    int lane = threadIdx.x & 63, wvv = threadIdx.x >> 6;
    float rn = waveReduceSum(nll);
    if (lane == 0) lds[wvv] = rn;
    __syncthreads();
    float totN = (threadIdx.x == 0) ? lds[0] + lds[1] + lds[2] + lds[3] : 0.f;
    __syncthreads();
    float rm = waveReduceSum(mask);
    if (lane == 0) lds[wvv] = rm;
    __syncthreads();
    if (threadIdx.x == 0) {
        pNll[blockIdx.x]  = totN;
        pMask[blockIdx.x] = lds[0] + lds[1] + lds[2] + lds[3];
        __threadfence();
        unsigned old = atomicAdd((unsigned*)counter, 1u);
        isLast = (old == NPART - 1);
    }
    __syncthreads();
    if (isLast) {
        __threadfence();
        int t = threadIdx.x;
        float n = waveReduceSum(pNll[t]);
        float m = waveReduceSum(pMask[t]);
        if (lane == 0) { lds[wvv] = n; lds[4 + wvv] = m; }
        __syncthreads();
        if (t == 0) {
            float tn = lds[0] + lds[1] + lds[2] + lds[3];
            float tm = lds[4] + lds[5] + lds[6] + lds[7];
            const float inv = 1.f / (float)NBS;
            outv[0] = (tn * inv) * (1.f + tm * inv);
        }
    }
}

extern "C" void kernel_launch(void* const* d_in, const int* in_sizes, int n_in,
                              void* d_out, int out_size, void* d_ws, size_t ws_size,
                              hipStream_t stream) {
    const float* x      = (const float*)d_in[0];
    const int*   target = (const int*)d_in[1];
    const int*   ttype  = (const int*)d_in[2];
    const float* tval   = (const float*)d_in[3];
    const float* coeff  = (const float*)d_in[4];
    const float* harm   = (const float*)d_in[5];

    float* ws    = (float*)d_ws;
    int*   ctr   = (int*)ws;                     // 4 ints
    float* pNll  = ws + 4;                       // 256
    float* pMask = pNll + NPART;                 // 256
    float* xtArr = pMask + NPART;                // 65536 (offset 516, 16B-aligned)
    float* pSum  = xtArr + NBS;                  // 16*65536
    float* pBest = pSum + (size_t)NCHUNK * NBS;  // 16*65536
    int*   pIdx  = (int*)(pBest + (size_t)NCHUNK * NBS);

    hl_tile<<<BB * NCHUNK, 512, 0, stream>>>(x, target, ctr, pSum, pBest,
                                             pIdx, xtArr);
    hl_comb<<<NBS / 256, 256, 0, stream>>>(target, ttype, tval, coeff, harm,
                                           pSum, pBest, pIdx, xtArr,
                                           pNll, pMask, ctr, (float*)d_out);
}

// Round 7
// 44.873 us; speedup vs baseline: 1.8778x; 1.0468x over previous
//
#include <hip/hip_runtime.h>
#include <hip/hip_fp16.h>

#define BB 32
#define SS 2048
#define VV 516
#define NBS (BB * SS)      // 65536
#define NCHUNK 16
#define NPART 256          // comb block count
#define BUFE (8 * 2048)    // halves per staging buffer

struct alignas(8) h4 { __half2 a, b; };

__device__ inline float waveReduceSum(float v) {
    #pragma unroll
    for (int o = 32; o > 0; o >>= 1) v += __shfl_down(v, o, 64);
    return v;
}

// One block per (b, v-chunk), 512 threads (8 waves).  Single HBM sweep.
// Double-buffered fp16 LDS staging of exp(x); per 8-row sub-chunk:
//   finish(k): wave wv exps its prefetched row, writes LDS buf[k&1], row-sum
//   barrier
//   prefetch(k+1): issue global loads (in flight under the rest)
//   phase2(k): batch-read 8 rows from LDS into regs, accumulate sum/argmax
// One barrier per sub-chunk (buffer parity keeps writers a barrier behind
// readers).  Argmax uses e * rcp(rowSum) == softmax_S value (monotone equiv
// of x - lseS).  Target logit gathered from LDS (xt = log(e)).
__global__ __launch_bounds__(512, 4) void hl_tile(const float* __restrict__ x,
                                                  const int* __restrict__ target,
                                                  int* __restrict__ ctr,
                                                  float* __restrict__ pSum,
                                                  float* __restrict__ pBest,
                                                  int* __restrict__ pIdx,
                                                  float* __restrict__ xtArr) {
    __shared__ __half ldsE[2 * BUFE];     // 64 KB
    __shared__ float sRcp[2][8];

    if (blockIdx.x == 0 && threadIdx.x == 0) ctr[0] = 0;   // comb finalize ctr

    const int c = blockIdx.x & 15, b = blockIdx.x >> 4;
    const int v0 = 32 * c + (c > 12 ? c - 12 : 0);          // 12x32 + 4x33
    const int nv = (c >= 12) ? 33 : 32;
    const int nsub = (nv + 7) >> 3;                         // 4 or 5
    const int tid = threadIdx.x, lane = tid & 63, wv = tid >> 6;
    const int s0 = tid << 2;
    const int bs = b * SS + s0;

    int4 tg4 = *(const int4*)(target + bs);
    int tg[4] = {tg4.x, tg4.y, tg4.z, tg4.w};

    float sum[4] = {0.f, 0.f, 0.f, 0.f};
    float best[4] = {-1.f, -1.f, -1.f, -1.f};
    float xt[4] = {0.f, 0.f, 0.f, 0.f};
    int bi[4] = {v0, v0, v0, v0};

    const float* xb = x + (size_t)(b * VV + v0) * SS;
    float4 vb[8];

    // prefetch sub-chunk 0 (wave wv owns row wv; m0 >= 8 always)
    {
        const float* row = xb + (size_t)wv * SS;
        #pragma unroll
        for (int j = 0; j < 8; ++j)
            vb[j] = *(const float4*)(row + j * 256 + lane * 4);
    }

    for (int k = 0; k < nsub; ++k) {
        const int m = (nv - k * 8 < 8) ? (nv - k * 8) : 8;
        const int kb = k & 1;
        // ---- finish(k): exp, fp16 pack, LDS write, row-sum ----
        if (wv < m) {                                       // wave-uniform
            __half* dst = ldsE + kb * BUFE + wv * 2048;
            float a0 = 0.f, a1 = 0.f, a2 = 0.f, a3 = 0.f;
            #pragma unroll
            for (int j = 0; j < 8; ++j) {
                float ex = __expf(vb[j].x), ey = __expf(vb[j].y);
                float ez = __expf(vb[j].z), ew = __expf(vb[j].w);
                h4 h;
                h.a = __halves2half2(__float2half_rn(ex), __float2half_rn(ey));
                h.b = __halves2half2(__float2half_rn(ez), __float2half_rn(ew));
                *(h4*)(dst + j * 256 + lane * 4) = h;
                a0 += ex; a1 += ey; a2 += ez; a3 += ew;
            }
            float ssum = waveReduceSum((a0 + a1) + (a2 + a3));
            if (lane == 0) sRcp[kb][wv] = 1.f / ssum;
        }
        __syncthreads();
        // ---- prefetch(k+1): loads in flight under phase2 + next finish ----
        if (k + 1 < nsub) {
            int m2 = nv - (k + 1) * 8;
            if (wv < m2) {
                const float* row = xb + (size_t)((k + 1) * 8 + wv) * SS;
                #pragma unroll
                for (int j = 0; j < 8; ++j)
                    vb[j] = *(const float4*)(row + j * 256 + lane * 4);
            }
        }
        // ---- phase2(k): batch-read m rows, accumulate ----
        const __half* src = ldsE + kb * BUFE + s0;
        if (m == 8) {
            h4 r[8];
            #pragma unroll
            for (int i = 0; i < 8; ++i)
                r[i] = *(const h4*)(src + i * 2048);
            #pragma unroll
            for (int i = 0; i < 8; ++i) {
                float rc = sRcp[kb][i];
                int vg = v0 + k * 8 + i;
                float e0 = __low2float(r[i].a), e1 = __high2float(r[i].a);
                float e2 = __low2float(r[i].b), e3 = __high2float(r[i].b);
                sum[0] += e0; sum[1] += e1; sum[2] += e2; sum[3] += e3;
                float c0 = e0 * rc, c1 = e1 * rc, c2 = e2 * rc, c3 = e3 * rc;
                if (c0 > best[0]) { best[0] = c0; bi[0] = vg; }
                if (c1 > best[1]) { best[1] = c1; bi[1] = vg; }
                if (c2 > best[2]) { best[2] = c2; bi[2] = vg; }
                if (c3 > best[3]) { best[3] = c3; bi[3] = vg; }
            }
        } else {
            for (int v = 0; v < m; ++v) {
                h4 r = *(const h4*)(src + v * 2048);
                float rc = sRcp[kb][v];
                int vg = v0 + k * 8 + v;
                float e0 = __low2float(r.a), e1 = __high2float(r.a);
                float e2 = __low2float(r.b), e3 = __high2float(r.b);
                sum[0] += e0; sum[1] += e1; sum[2] += e2; sum[3] += e3;
                float c0 = e0 * rc, c1 = e1 * rc, c2 = e2 * rc, c3 = e3 * rc;
                if (c0 > best[0]) { best[0] = c0; bi[0] = vg; }
                if (c1 > best[1]) { best[1] = c1; bi[1] = vg; }
                if (c2 > best[2]) { best[2] = c2; bi[2] = vg; }
                if (c3 > best[3]) { best[3] = c3; bi[3] = vg; }
            }
        }
        // ---- target gather from this sub-chunk's buffer ----
        #pragma unroll
        for (int i = 0; i < 4; ++i) {
            int lr = tg[i] - (v0 + k * 8);
            if (lr >= 0 && lr < m)
                xt[i] = __logf(__half2float(ldsE[kb * BUFE + lr * 2048 + s0 + i]));
        }
        // no trailing barrier: finish(k+1) writes buf[(k+1)&1]; buf[k&1] is
        // next written by finish(k+2), which is after barrier(k+1).
    }

    // ---- write per-chunk partials ----
    int o = c * NBS + bs;
    *(float4*)(pSum + o)  = make_float4(sum[0], sum[1], sum[2], sum[3]);
    *(float4*)(pBest + o) = make_float4(best[0], best[1], best[2], best[3]);
    *(int4*)(pIdx + o)    = make_int4(bi[0], bi[1], bi[2], bi[3]);
    int v1 = v0 + nv;
    #pragma unroll
    for (int i = 0; i < 4; ++i)
        if (tg[i] >= v0 && tg[i] < v1) xtArr[bs + i] = xt[i];
}

// Merge chunk partials per (b,s); nll + penalty mask; block partial sums;
// last block folds the 256 partials into the scalar output.  (R3-proven.)
__global__ __launch_bounds__(256) void hl_comb(const int* __restrict__ target,
                                               const int* __restrict__ ttype,
                                               const float* __restrict__ tval,
                                               const float* __restrict__ coeff,
                                               const float* __restrict__ harm,
                                               const float* __restrict__ pSum,
                                               const float* __restrict__ pBest,
                                               const int* __restrict__ pIdx,
                                               const float* __restrict__ xtArr,
                                               float* __restrict__ pNll,
                                               float* __restrict__ pMask,
                                               int* __restrict__ counter,
                                               float* __restrict__ outv) {
    __shared__ float lds[8];
    __shared__ bool isLast;
    int idx = blockIdx.x * 256 + threadIdx.x;            // (b,s) flat

    float sum = 0.f, best = -1e30f;
    int bestIdx = 0;
    #pragma unroll
    for (int c = 0; c < NCHUNK; ++c) {                   // ascending: first-idx ties
        int o = c * NBS + idx;
        sum += pSum[o];
        float sc = pBest[o];
        int ii = pIdx[o];
        if (sc > best) { best = sc; bestIdx = ii; }
    }
    int tgt = target[idx];
    float nll = __logf(sum) - xtArr[idx];

    int pt = ttype[bestIdx], tt = ttype[tgt];
    float pv = tval[bestIdx], tv = tval[tgt];
    float d = fabsf(pv - tv);
    float pw = (d == 7.f) ? harm[0] : (d == 5.f) ? harm[1] : (d == 3.f) ? harm[2]
             : (d == 4.f) ? harm[3] : (d == 1.f) ? harm[4] : (d == 2.f) ? harm[5]
             : harm[6];
    float w = (pt == 0) ? pw
            : (pt == 1) ? coeff[1] * d * (1.f / 160.f)
            : (pt == 2) ? coeff[2] * d * (1.f / 100.f)
            :             coeff[3] * d * (1.f / 128.f);
    float mask = (pt != tt) ? coeff[0] : w;

    int lane = threadIdx.x & 63, wvv = threadIdx.x >> 6;
    float rn = waveReduceSum(nll);
    if (lane == 0) lds[wvv] = rn;
    __syncthreads();
    float totN = (threadIdx.x == 0) ? lds[0] + lds[1] + lds[2] + lds[3] : 0.f;
    __syncthreads();
    float rm = waveReduceSum(mask);
    if (lane == 0) lds[wvv] = rm;
    __syncthreads();
    if (threadIdx.x == 0) {
        pNll[blockIdx.x]  = totN;
        pMask[blockIdx.x] = lds[0] + lds[1] + lds[2] + lds[3];
        __threadfence();
        unsigned old = atomicAdd((unsigned*)counter, 1u);
        isLast = (old == NPART - 1);
    }
    __syncthreads();
    if (isLast) {
        __threadfence();
        int t = threadIdx.x;
        float n = waveReduceSum(pNll[t]);
        float m = waveReduceSum(pMask[t]);
        if (lane == 0) { lds[wvv] = n; lds[4 + wvv] = m; }
        __syncthreads();
        if (t == 0) {
            float tn = lds[0] + lds[1] + lds[2] + lds[3];
            float tm = lds[4] + lds[5] + lds[6] + lds[7];
            const float inv = 1.f / (float)NBS;
            outv[0] = (tn * inv) * (1.f + tm * inv);
        }
    }
}

extern "C" void kernel_launch(void* const* d_in, const int* in_sizes, int n_in,
                              void* d_out, int out_size, void* d_ws, size_t ws_size,
                              hipStream_t stream) {
    const float* x      = (const float*)d_in[0];
    const int*   target = (const int*)d_in[1];
    const int*   ttype  = (const int*)d_in[2];
    const float* tval   = (const float*)d_in[3];
    const float* coeff  = (const float*)d_in[4];
    const float* harm   = (const float*)d_in[5];

    float* ws    = (float*)d_ws;
    int*   ctr   = (int*)ws;                     // 4 ints
    float* pNll  = ws + 4;                       // 256
    float* pMask = pNll + NPART;                 // 256
    float* xtArr = pMask + NPART;                // 65536 (offset 516 -> 16B-aligned)
    float* pSum  = xtArr + NBS;                  // 16*65536
    float* pBest = pSum + (size_t)NCHUNK * NBS;  // 16*65536
    int*   pIdx  = (int*)(pBest + (size_t)NCHUNK * NBS);

    hl_tile<<<BB * NCHUNK, 512, 0, stream>>>(x, target, ctr, pSum, pBest,
                                             pIdx, xtArr);
    hl_comb<<<NBS / 256, 256, 0, stream>>>(target, ttype, tval, coeff, harm,
                                           pSum, pBest, pIdx, xtArr,
                                           pNll, pMask, ctr, (float*)d_out);
}